// Round 9
// baseline (222.631 us; speedup 1.0000x reference)
//
#include <hip/hip_runtime.h>
#include <stdint.h>

// B=16 H=8 L=512 D=64; fp32 in/out. out = concat(output[128,512,64], attn[128,512,512]).
// Round-13: occupancy attack done right (round-9's mistake: kept 2 blocks/CU).
//   main4: 256thr/32 q-rows; waves = (i-tile ti, j-parity p); acc 16xf32x4 (64 VGPR)
//   -> launch_bounds(256,3). K in 64-row half-chunks, TRI-buffered (48KB), prefetch
//   depth 2, ONE barrier per phase (issue after barrier also guards buf reuse).
//   V tri-buffered in aliased region (prep V layout now half-chunk-major).
//   LDS ~51.7KB -> 3 blocks/CU = 12 waves/CU (was 8). Cross-wave softmax =
//   partner-pair LDS exchange; O = partner add via small LDS pass.
#define Ln 512
#define Dn 64
#define BHn 128
#define AOFF ((size_t)BHn*Ln*Dn)

typedef __attribute__((ext_vector_type(8))) short short8;   // 8 bf16 (4 VGPRs)
typedef __attribute__((ext_vector_type(4))) float f32x4;
typedef __attribute__((ext_vector_type(4))) unsigned int u32x4;
typedef __attribute__((ext_vector_type(2))) unsigned int u32x2;

__device__ __forceinline__ uint16_t f2bf(float f){
  uint32_t x = __float_as_uint(f);
  return (uint16_t)((x + 0x7FFFu + ((x>>16)&1u)) >> 16);   // RNE
}
__device__ __forceinline__ float bf2f(uint16_t u){ return __uint_as_float(((uint32_t)u)<<16); }
__device__ __forceinline__ uint32_t pack2(float a, float b){
  return (uint32_t)f2bf(a) | ((uint32_t)f2bf(b)<<16);
}
__device__ __forceinline__ void gld16(const uint16_t* g, uint16_t* l){
  __builtin_amdgcn_global_load_lds(
      (const __attribute__((address_space(1))) void*)g,
      (__attribute__((address_space(3))) void*)l, 16, 0, 0);
}

// ---- pre-pass: K -> KHI/KLO bf16 (row-major, XOR-swizzled k), V -> V^T bf16
// half-chunk-major: vtw idx = (bh<<15) + hc*4096 + d*64 + (jh ^ ((d&7)<<3)), hc=j/64.
// K idx (unchanged): (bh<<15) + j*64 + (k ^ ((j&7)<<3)).
// Grid (8,BHn) XCD-swizzled so ws lines land in the consuming XCD's L2.
extern "C" __global__ __launch_bounds__(256)
void attn_prep(const float* __restrict__ kg, const float* __restrict__ vg,
               uint16_t* __restrict__ khw, uint16_t* __restrict__ klw,
               uint16_t* __restrict__ vtw)
{
  const int t   = threadIdx.x;
  const int lin = blockIdx.x + (blockIdx.y << 3);
  const int xcd = lin & 7;
  const int by2 = lin >> 3;            // [0,128)
  const int bh  = (xcd << 4) + (by2 >> 3);
  const int hc  = by2 & 7;             // 64-row half-chunk
  const size_t base = (size_t)bh*(Ln*Dn);
  const size_t wsbh = (size_t)bh << 15;

  // K: 64 rows; thread -> row grow, k-half skh, w2 pair
  {
    const int grow = hc*64 + (t>>2);
    const int skh  = (t>>1)&1;
    const int w2b  = (t&1)*2;
    const float* kr = kg + base + (size_t)grow*Dn + skh*32 + w2b*8;
    const int sx = (grow&7)<<3;
    #pragma unroll
    for (int w=0; w<2; ++w){
      const int w2 = w2b + w;
      f32x4 x0 = *(const f32x4*)(kr + w*8);
      f32x4 x1 = *(const f32x4*)(kr + w*8 + 4);
      uint32_t hw[4], lw[4];
      #pragma unroll
      for (int pi=0; pi<4; ++pi){
        float a0 = (pi<2) ? x0[pi*2]   : x1[(pi-2)*2];
        float a1 = (pi<2) ? x0[pi*2+1] : x1[(pi-2)*2+1];
        uint16_t h0 = f2bf(a0), h1 = f2bf(a1);
        hw[pi] = (uint32_t)h0 | ((uint32_t)h1<<16);
        lw[pi] = (uint32_t)f2bf(a0 - bf2f(h0)) | ((uint32_t)f2bf(a1 - bf2f(h1))<<16);
      }
      const size_t di = wsbh + (size_t)grow*64 + ((skh*32 + w2*8) ^ sx);
      *(u32x4*)(khw + di) = (u32x4){hw[0],hw[1],hw[2],hw[3]};
      *(u32x4*)(klw + di) = (u32x4){lw[0],lw[1],lw[2],lw[3]};
    }
  }

  // V: 64 rows, 4x4 register transpose -> VT[hc][d][jh], swizzled
  {
    const int j0 = (t>>4)*4;            // half-chunk-local j quad [0,64)
    const int d0 = (t&15)*4;
    const float* vr = vg + base + (size_t)(hc*64 + j0)*Dn + d0;
    f32x4 r0 = *(const f32x4*)(vr);
    f32x4 r1 = *(const f32x4*)(vr + Dn);
    f32x4 r2 = *(const f32x4*)(vr + 2*Dn);
    f32x4 r3 = *(const f32x4*)(vr + 3*Dn);
    #pragma unroll
    for (int qd=0; qd<4; ++qd){
      const int d = d0 + qd;
      u32x2 w; w.x = pack2(r0[qd], r1[qd]); w.y = pack2(r2[qd], r3[qd]);
      *(u32x2*)(vtw + wsbh + hc*4096 + d*64 + (j0 ^ ((d&7)<<3))) = w;
    }
  }
}

// ---- main4: 32 q-rows/block; wave = (ti = wv>>1, parity p = wv&1) over j ----
extern "C" __global__ __launch_bounds__(256, 3)
void attn_main4(const float* __restrict__ qg, const float* __restrict__ mg,
                const uint16_t* __restrict__ khw, const uint16_t* __restrict__ klw,
                const uint16_t* __restrict__ vtw, float* __restrict__ outg)
{
  // BIG 48KB (halves): QK tri-buf Kb = [b*8192, b*8192+8192) = KH[4096]+KL[4096]
  //   PV (aliased): VT tri-buf [b*4096, +4096); PW [12288:14848) (4 waves x 640)
  //   epilogue: ORf f32 [0:2176) floats (aliased after barrier)
  __shared__ __align__(16) uint16_t BIG[24576];
  __shared__ float CMV[512];
  __shared__ float MXW[64], SMW[64];

  const int t    = threadIdx.x;
  const int lane = t & 63;
  const int wv   = t >> 6;
  const int li   = lane & 15;
  const int lq   = lane >> 4;
  const int ti   = wv >> 1;            // wave's i-tile (0..1)
  const int p    = wv & 1;             // wave's j-parity
  const int kx   = (li&7)<<3;          // swizzle XOR (halves)

  // XCD swizzle: hw xcd = (bx + 16*by)%8 = bx&7; XCD k owns bh [k*16,k*16+16)
  const int lin = blockIdx.x + (blockIdx.y << 4);   // gridDim.x = 16
  const int xcd = lin & 7;
  const int jj  = lin >> 3;            // [0,256)
  const int bh  = (xcd << 4) + (jj >> 4);
  const int b   = bh >> 3;
  const int i0  = (jj & 15) * 32;      // block's 32 query rows

  const size_t base = (size_t)bh*(Ln*Dn);
  const float* mrow = mg + b*Ln;
  const size_t wsbh = (size_t)bh << 15;

  uint16_t* PW = BIG + 12288 + wv*640;   // 16 rows x 40 halves, wave-private

  auto issueK = [&](int hc, int bs){     // 4 vmem ops/wave
    const size_t so = wsbh + ((size_t)hc<<12) + (wv<<10) + (lane<<3);
    uint16_t* dh = BIG + bs*8192 + (wv<<10);
    #pragma unroll
    for (int i=0;i<2;++i){
      gld16(khw + so + i*512, dh + i*512);
      gld16(klw + so + i*512, dh + 4096 + i*512);
    }
  };
  auto issueV = [&](int hc, int bs){     // 2 vmem ops/wave
    const size_t so = wsbh + ((size_t)hc<<12) + (wv<<10) + (lane<<3);
    uint16_t* dv = BIG + bs*4096 + (wv<<10);
    #pragma unroll
    for (int i=0;i<2;++i) gld16(vtw + so + i*512, dv + i*512);
  };

  // ---- prologue: Q + mask loads FIRST, then depth-2 K DMA ----
  const float* qrow = qg + base + (size_t)(i0 + ti*16 + li)*Dn;
  f32x4 qx0a = *(const f32x4*)(qrow + lq*8);
  f32x4 qx0b = *(const f32x4*)(qrow + lq*8 + 4);
  f32x4 qx1a = *(const f32x4*)(qrow + 32 + lq*8);
  f32x4 qx1b = *(const f32x4*)(qrow + 32 + lq*8 + 4);
  float m0 = mrow[t], m1 = mrow[t+256];
  float mv = mrow[i0 + ti*16 + li];

  issueK(0, 0);
  issueK(1, 1);

  CMV[t]     = (m0 < -9000.f) ? 1e9f : m0;
  CMV[t+256] = (m1 < -9000.f) ? 1e9f : m1;
  const float rmv = (mv < -9000.f) ? 1e9f : mv;

  short8 qhi[2], qlo[2];
  #pragma unroll
  for (int kt=0; kt<2; ++kt){
    f32x4 xa = kt ? qx1a : qx0a;
    f32x4 xb = kt ? qx1b : qx0b;
    #pragma unroll
    for (int e=0; e<8; ++e){
      float x = (e<4) ? xa[e] : xb[e-4];
      uint16_t h = f2bf(x);
      qhi[kt][e] = (short)h;
      qlo[kt][e] = (short)f2bf(x - bf2f(h));
    }
  }

  // acc[hc*2+u]: S^T tile jt = 4*hc + 2*u + p; lane holds S^T[jt*16+lq*4+r][i0+ti*16+li]
  f32x4 acc[16];
  #pragma unroll
  for (int m=0; m<16; ++m) acc[m] = (f32x4)0.f;

  // ---- QK: 8 half-chunks, tri-buffered, depth-2 prefetch, ONE barrier per phase ----
  #pragma unroll
  for (int hc=0; hc<8; ++hc){
    if (hc<7) asm volatile("s_waitcnt vmcnt(4)" ::: "memory");  // K_hc landed; K_hc+1 flies
    else      asm volatile("s_waitcnt vmcnt(0)" ::: "memory");  // K7 landed
    __builtin_amdgcn_sched_barrier(0);
    __builtin_amdgcn_s_barrier();            // all portions landed; also: all waves done
    __builtin_amdgcn_sched_barrier(0);       //   reading buf (hc-1)%3 -> reuse safe
    if (hc<6) issueK(hc+2, (hc+2)%3);
    if (hc==7){ issueV(0, 0); issueV(1, 1); }  // K buf0 free (last read hc6)
    const uint16_t* KHp = BIG + (hc%3)*8192;
    const uint16_t* KLp = KHp + 4096;
    __builtin_amdgcn_s_setprio(1);
    #pragma unroll
    for (int u=0; u<2; ++u){
      const int row = (2*u + p)*16 + li;     // half-chunk-local j row
      #pragma unroll
      for (int kt=0; kt<2; ++kt){
        const int idx = row*64 + ((kt*32 + lq*8) ^ kx);
        short8 kh = *(const short8*)(KHp + idx);
        short8 kl = *(const short8*)(KLp + idx);
        f32x4 A = acc[hc*2+u];
        A = __builtin_amdgcn_mfma_f32_16x16x32_bf16(kh, qhi[kt], A, 0,0,0);
        A = __builtin_amdgcn_mfma_f32_16x16x32_bf16(kl, qhi[kt], A, 0,0,0);
        A = __builtin_amdgcn_mfma_f32_16x16x32_bf16(kh, qlo[kt], A, 0,0,0);
        acc[hc*2+u] = A;
      }
    }
    __builtin_amdgcn_s_setprio(0);
  }

  // ---- mask + scale (fp32 order matches ref) ----
  #pragma unroll
  for (int m=0; m<16; ++m){
    const int jt = 4*(m>>1) + 2*(m&1) + p;
    f32x4 cm = *(const f32x4*)(CMV + jt*16 + lq*4);
    #pragma unroll
    for (int r=0; r<4; ++r)
      acc[m][r] = (acc[m][r]*0.125f - rmv) - cm[r];
  }

  // ---- softmax: wave-local over 256 j, then partner-pair exchange (V0/V1 DMA fly) ----
  float mx = -3.4e38f;
  #pragma unroll
  for (int m=0; m<16; ++m)
    #pragma unroll
    for (int r=0; r<4; ++r) mx = fmaxf(mx, acc[m][r]);
  mx = fmaxf(mx, __shfl_xor(mx, 16));
  mx = fmaxf(mx, __shfl_xor(mx, 32));
  if (lane < 16) MXW[wv*16 + lane] = mx;
  asm volatile("s_waitcnt lgkmcnt(0)" ::: "memory");
  __builtin_amdgcn_s_barrier();
  const float mxa = fmaxf(mx, MXW[(wv^1)*16 + li]);

  float sum = 0.f;
  #pragma unroll
  for (int m=0; m<16; ++m)
    #pragma unroll
    for (int r=0; r<4; ++r){ float e = __expf(acc[m][r]-mxa); acc[m][r] = e; sum += e; }
  sum += __shfl_xor(sum, 16);
  sum += __shfl_xor(sum, 32);
  if (lane < 16) SMW[wv*16 + lane] = sum;
  asm volatile("s_waitcnt lgkmcnt(0)" ::: "memory");
  __builtin_amdgcn_s_barrier();
  const float inv = 1.0f/(sum + SMW[(wv^1)*16 + li]);
  #pragma unroll
  for (int m=0; m<16; ++m) acc[m] = acc[m]*inv;   // normalized P (also attn output)

  // ---- PV: tri-buffered V, interleaved attn stores; partial O per parity ----
  f32x4 oacc[4];
  #pragma unroll
  for (int dt=0; dt<4; ++dt) oacc[dt] = (f32x4)0.f;

  float* arow = outg + AOFF + (size_t)bh*Ln*Ln + (size_t)(i0 + ti*16 + li)*Ln;
  const int jb = (2*(lq>>1) + p)*16 + (lq&1)*8;   // V^T half-chunk-local j for A-frag

  #pragma unroll
  for (int hc=0; hc<8; ++hc){
    u32x2 pw0, pw1;                     // P pack hoisted (pure VALU on ready acc)
    { const f32x4 a0 = acc[hc*2], a1 = acc[hc*2+1];
      pw0.x = pack2(a0[0],a0[1]); pw0.y = pack2(a0[2],a0[3]);
      pw1.x = pack2(a1[0],a1[1]); pw1.y = pack2(a1[2],a1[3]); }
    if (hc==0)      asm volatile("s_waitcnt vmcnt(2)" ::: "memory");  // V0 done; V1 flies
    else if (hc<7)  asm volatile("s_waitcnt vmcnt(4)" ::: "memory");  // V_hc done; V_hc+1 + prev stores fly
    else            asm volatile("s_waitcnt vmcnt(2)" ::: "memory");  // V7 done; stores6 fly
    __builtin_amdgcn_sched_barrier(0);
    __builtin_amdgcn_s_barrier();        // all portions landed; buf (hc-1)%3 reuse safe
    __builtin_amdgcn_sched_barrier(0);
    if (hc<6) issueV(hc+2, (hc+2)%3);
    *(u32x2*)(PW + li*40 + lq*4)      = pw0;    // P rows (wave-private)
    *(u32x2*)(PW + li*40 + 16 + lq*4) = pw1;
    asm volatile("s_waitcnt lgkmcnt(0)" ::: "memory");
    __builtin_amdgcn_sched_barrier(0);
    const uint16_t* VTp = BIG + (hc%3)*4096;
    __builtin_amdgcn_s_setprio(1);
    short8 pf = *(const short8*)(PW + li*40 + lq*8);                  // P^T B-frag
    #pragma unroll
    for (int dt=0; dt<4; ++dt){
      short8 vb = *(const short8*)(VTp + (dt*16+li)*64 + (jb ^ kx));  // V^T A-frag
      oacc[dt] = __builtin_amdgcn_mfma_f32_16x16x32_bf16(vb, pf, oacc[dt], 0,0,0);
    }
    __builtin_amdgcn_s_setprio(0);
    // attn stores for this half-chunk's 2 tiles (normal stores; L2 merges lines)
    *(f32x4*)(arow + (4*hc + p)*16 + lq*4)     = acc[hc*2];
    *(f32x4*)(arow + (4*hc + 2 + p)*16 + lq*4) = acc[hc*2+1];
  }

  // ---- O: partner-pair reduce via small LDS pass (aliases BIG after barrier) ----
  __builtin_amdgcn_sched_barrier(0);
  __builtin_amdgcn_s_barrier();          // all PV LDS reads done before alias
  __builtin_amdgcn_sched_barrier(0);
  float* ORf = (float*)BIG;              // [2][64][17] f32 = 8704B
  if (p == 1){
    #pragma unroll
    for (int dt=0; dt<4; ++dt)
      #pragma unroll
      for (int r=0; r<4; ++r)
        ORf[ti*1088 + (dt*16 + lq*4 + r)*17 + li] = oacc[dt][r];
  }
  asm volatile("s_waitcnt lgkmcnt(0)" ::: "memory");
  __builtin_amdgcn_s_barrier();
  if (p == 0){
    #pragma unroll
    for (int dt=0; dt<4; ++dt){
      f32x4 o;
      #pragma unroll
      for (int r=0; r<4; ++r)
        o[r] = oacc[dt][r] + ORf[ti*1088 + (dt*16 + lq*4 + r)*17 + li];
      *(f32x4*)(outg + base + (size_t)(i0 + ti*16 + li)*Dn + dt*16 + lq*4) = o;
    }
  }
}

// ---------------- fallback (round-5 kernel) if workspace is too small ----------------
#define KSTR  72
#define VTSTR 136
#define FPSTRH 136

extern "C" __global__ __launch_bounds__(256, 2)
void attn_mfma(const float* __restrict__ qg, const float* __restrict__ kg,
               const float* __restrict__ vg, const float* __restrict__ mg,
               float* __restrict__ outg)
{
  __shared__ uint4 ldsraw[(36864 + 2048)/16];
  uint16_t* KHI = (uint16_t*)ldsraw;
  uint16_t* KLO = KHI + 128*KSTR;
  uint16_t* VT  = (uint16_t*)ldsraw;
  float*    CMV = (float*)((char*)ldsraw + 36864);

  const int t    = threadIdx.x;
  const int lane = t & 63;
  const int wv   = t >> 6;
  const int li   = lane & 15;
  const int lq   = lane >> 4;

  const int lin = blockIdx.x + (blockIdx.y << 3);
  const int xcd = lin & 7;
  const int jj  = lin >> 3;
  const int bh  = (xcd << 4) + (jj >> 3);
  const int b   = bh >> 3;
  const int i0  = (jj & 7)*64 + wv*16;

  const size_t base = (size_t)bh*(Ln*Dn);
  const float* mrow = mg + b*Ln;

  uint16_t* PW = (uint16_t*)((char*)ldsraw + 17408 + wv*(16*FPSTRH*2));

  {
    float m0 = mrow[t], m1 = mrow[t+256];
    CMV[t]     = (m0 < -9000.f) ? 1e9f : m0;
    CMV[t+256] = (m1 < -9000.f) ? 1e9f : m1;
  }

  short8 qhi[2], qlo[2];
  {
    const float* qrow = qg + base + (size_t)(i0 + li)*Dn;
    #pragma unroll
    for (int kt=0; kt<2; ++kt){
      const float* p = qrow + kt*32 + lq*8;
      f32x4 x0 = *(const f32x4*)p;
      f32x4 x1 = *(const f32x4*)(p+4);
      #pragma unroll
      for (int e=0; e<8; ++e){
        float x = (e<4) ? x0[e] : x1[e-4];
        uint16_t h = f2bf(x);
        qhi[kt][e] = (short)h;
        qlo[kt][e] = (short)f2bf(x - bf2f(h));
      }
    }
  }

  f32x4 acc[32];
  #pragma unroll
  for (int j=0; j<32; ++j) acc[j] = (f32x4)0.f;

  const int sj = t>>1, skh = t&1;
  #pragma unroll
  for (int c=0; c<4; ++c){
    __syncthreads();
    {
      const float* kr = kg + base + (size_t)(c*128 + sj)*Dn + skh*32;
      uint16_t* dhi = KHI + sj*KSTR + skh*32;
      uint16_t* dlo = KLO + sj*KSTR + skh*32;
      #pragma unroll
      for (int w2=0; w2<4; ++w2){
        f32x4 x0 = *(const f32x4*)(kr + w2*8);
        f32x4 x1 = *(const f32x4*)(kr + w2*8 + 4);
        uint32_t hw[4], lw[4];
        #pragma unroll
        for (int pi=0; pi<4; ++pi){
          float a0 = (pi<2) ? x0[pi*2]   : x1[(pi-2)*2];
          float a1 = (pi<2) ? x0[pi*2+1] : x1[(pi-2)*2+1];
          uint16_t h0 = f2bf(a0), h1 = f2bf(a1);
          hw[pi] = (uint32_t)h0 | ((uint32_t)h1<<16);
          lw[pi] = (uint32_t)f2bf(a0 - bf2f(h0)) | ((uint32_t)f2bf(a1 - bf2f(h1))<<16);
        }
        *(u32x4*)(dhi + w2*8) = (u32x4){hw[0],hw[1],hw[2],hw[3]};
        *(u32x4*)(dlo + w2*8) = (u32x4){lw[0],lw[1],lw[2],lw[3]};
      }
    }
    __syncthreads();
    #pragma unroll
    for (int jt=0; jt<8; ++jt){
      #pragma unroll
      for (int kt=0; kt<2; ++kt){
        const int off = (jt*16 + li)*KSTR + kt*32 + lq*8;
        short8 kh = *(const short8*)(KHI + off);
        short8 kl = *(const short8*)(KLO + off);
        f32x4 A = acc[c*8+jt];
        A = __builtin_amdgcn_mfma_f32_16x16x32_bf16(kh, qhi[kt], A, 0,0,0);
        A = __builtin_amdgcn_mfma_f32_16x16x32_bf16(kl, qhi[kt], A, 0,0,0);
        A = __builtin_amdgcn_mfma_f32_16x16x32_bf16(kh, qlo[kt], A, 0,0,0);
        acc[c*8+jt] = A;
      }
    }
  }

  {
    float mv = mrow[i0 + li];
    const float rmv = (mv < -9000.f) ? 1e9f : mv;
    #pragma unroll
    for (int jt=0; jt<32; ++jt){
      f32x4 cm = *(const f32x4*)(CMV + jt*16 + lq*4);
      #pragma unroll
      for (int r=0; r<4; ++r)
        acc[jt][r] = (acc[jt][r]*0.125f - rmv) - cm[r];
    }
  }
  float mx = -3.4e38f;
  #pragma unroll
  for (int jt=0; jt<32; ++jt)
    #pragma unroll
    for (int r=0; r<4; ++r) mx = fmaxf(mx, acc[jt][r]);
  mx = fmaxf(mx, __shfl_xor(mx, 16));
  mx = fmaxf(mx, __shfl_xor(mx, 32));
  float sum = 0.f;
  #pragma unroll
  for (int jt=0; jt<32; ++jt)
    #pragma unroll
    for (int r=0; r<4; ++r){ float e = __expf(acc[jt][r]-mx); acc[jt][r] = e; sum += e; }
  sum += __shfl_xor(sum, 16);
  sum += __shfl_xor(sum, 32);
  const float inv = 1.0f/sum;

  {
    float* arow = outg + AOFF + (size_t)bh*Ln*Ln + (size_t)(i0+li)*Ln;
    #pragma unroll
    for (int jt=0; jt<32; ++jt){
      f32x4 p = acc[jt]*inv;
      acc[jt] = p;
      *(f32x4*)(arow + jt*16 + lq*4) = p;
    }
  }

  f32x4 oacc[4];
  #pragma unroll
  for (int dt=0; dt<4; ++dt) oacc[dt] = (f32x4)0.f;

  #pragma unroll
  for (int c=0; c<4; ++c){
    __syncthreads();
    #pragma unroll
    for (int it=0; it<2; ++it){
      const int j0 = (t>>4)*4 + it*64;
      const int d0 = (t&15)*4;
      const float* vr = vg + base + (size_t)(c*128 + j0)*Dn + d0;
      f32x4 r0 = *(const f32x4*)(vr);
      f32x4 r1 = *(const f32x4*)(vr + Dn);
      f32x4 r2 = *(const f32x4*)(vr + 2*Dn);
      f32x4 r3 = *(const f32x4*)(vr + 3*Dn);
      #pragma unroll
      for (int qd=0; qd<4; ++qd){
        u32x2 w; w.x = pack2(r0[qd], r1[qd]); w.y = pack2(r2[qd], r3[qd]);
        *(u32x2*)(VT + (d0+qd)*VTSTR + j0) = w;
      }
    }
    __syncthreads();
    #pragma unroll
    for (int jtl=0; jtl<8; ++jtl){
      const f32x4 p = acc[c*8+jtl];
      u32x2 w; w.x = pack2(p[0], p[1]); w.y = pack2(p[2], p[3]);
      *(u32x2*)(PW + li*FPSTRH + jtl*16 + lq*4) = w;
    }
    asm volatile("s_waitcnt lgkmcnt(0)" ::: "memory");
    #pragma unroll
    for (int c32=0; c32<4; ++c32){
      short8 pf = *(const short8*)(PW + li*FPSTRH + c32*32 + lq*8);
      #pragma unroll
      for (int dt=0; dt<4; ++dt){
        short8 vb = *(const short8*)(VT + (dt*16+li)*VTSTR + c32*32 + lq*8);
        oacc[dt] = __builtin_amdgcn_mfma_f32_16x16x32_bf16(vb, pf, oacc[dt], 0,0,0);
      }
    }
  }

  #pragma unroll
  for (int dt=0; dt<4; ++dt)
    *(f32x4*)(outg + base + (size_t)(i0+li)*Dn + dt*16 + lq*4) = oacc[dt];
}

extern "C" void kernel_launch(void* const* d_in, const int* in_sizes, int n_in,
                              void* d_out, int out_size, void* d_ws, size_t ws_size,
                              hipStream_t stream)
{
  (void)in_sizes; (void)n_in; (void)out_size;
  const float* qg = (const float*)d_in[0];
  const float* kg = (const float*)d_in[1];
  const float* vg = (const float*)d_in[2];
  const float* mg = (const float*)d_in[3];
  float* outg = (float*)d_out;

  const size_t WS_NEED = 25165824;   // KHI 8.39MB + KLO 8.39MB + VT 8.39MB
  if (d_ws && ws_size >= WS_NEED){
    uint16_t* khw = (uint16_t*)d_ws;
    uint16_t* klw = (uint16_t*)((char*)d_ws + 8388608);
    uint16_t* vtw = (uint16_t*)((char*)d_ws + 16777216);
    attn_prep<<<dim3(8, BHn), 256, 0, stream>>>(kg, vg, khw, klw, vtw);
    attn_main4<<<dim3(16, BHn), 256, 0, stream>>>(qg, mg, khw, klw, vtw, outg);
  } else {
    attn_mfma<<<dim3(Ln/64, BHn), 256, 0, stream>>>(qg, kg, vg, mg, outg);
  }
}

// Round 10
// 214.786 us; speedup vs baseline: 1.0365x; 1.0365x over previous
//
#include <hip/hip_runtime.h>
#include <stdint.h>

// B=16 H=8 L=512 D=64; fp32 in/out. out = concat(output[128,512,64], attn[128,512,512]).
// Round-14 = Round-12 base REVERT (best measured: 216.2us) + prep micro-fix only.
//   Round-13 post-mortem: i-split main is REGISTER-capped at 2 waves/SIMD
//   (acc[32]=128 regs + 104 VGPR ~= 232/512); all three j-split occupancy
//   restructures (R6/R9/R13) lost more in cross-wave machinery than they gained.
//   Main kernel is verbatim round-12. Prep: grid (8,BHn)->(16,BHn) 32-row
//   quarter-chunks (2048 blocks, 8/CU TLP) with XCD-aligned mapping so each bh's
//   ws writes land in the L2 of the XCD (bh>>4) that main reads them from.
#define Ln 512
#define Dn 64
#define BHn 128
#define AOFF ((size_t)BHn*Ln*Dn)

typedef __attribute__((ext_vector_type(8))) short short8;   // 8 bf16 (4 VGPRs)
typedef __attribute__((ext_vector_type(4))) float f32x4;
typedef __attribute__((ext_vector_type(2))) float f32x2;
typedef __attribute__((ext_vector_type(4))) unsigned int u32x4;
typedef __attribute__((ext_vector_type(2))) unsigned int u32x2;

__device__ __forceinline__ uint16_t f2bf(float f){
  uint32_t x = __float_as_uint(f);
  return (uint16_t)((x + 0x7FFFu + ((x>>16)&1u)) >> 16);   // RNE
}
__device__ __forceinline__ float bf2f(uint16_t u){ return __uint_as_float(((uint32_t)u)<<16); }
__device__ __forceinline__ uint32_t pack2(float a, float b){
  return (uint32_t)f2bf(a) | ((uint32_t)f2bf(b)<<16);
}
__device__ __forceinline__ void gld16(const uint16_t* g, uint16_t* l){
  __builtin_amdgcn_global_load_lds(
      (const __attribute__((address_space(1))) void*)g,
      (__attribute__((address_space(3))) void*)l, 16, 0, 0);
}

// ---- pre-pass: K -> KHI/KLO bf16, V -> V^T bf16, XOR-swizzled, chunk-major in ws ----
// K chunk layout (halves, per bh per chunk of 128 j): idx = j*64 + (k ^ ((j&7)<<3))
// V chunk layout (halves): idx = d*128 + (jl ^ ((d&7)<<3)), jl = j within chunk
// Grid (16,BHn), XCD-aligned: lin&7 = hw XCD; bh = (xcd<<4)+(rest>>4) so each bh's
// writes run on (and cache into) the XCD whose main blocks consume them.
// 32-row quarter-chunks: c = sub>>2, q = sub&3.
extern "C" __global__ __launch_bounds__(256)
void attn_prep(const float* __restrict__ kg, const float* __restrict__ vg,
               uint16_t* __restrict__ khw, uint16_t* __restrict__ klw,
               uint16_t* __restrict__ vtw)
{
  const int t    = threadIdx.x;
  const int lin  = blockIdx.x + (blockIdx.y << 4);
  const int xcd  = lin & 7;
  const int rest = lin >> 3;           // [0,256)
  const int bh   = (xcd << 4) + (rest >> 4);
  const int sub  = rest & 15;
  const int c    = sub >> 2;           // j-chunk of 128
  const int q    = sub & 3;            // 32-row quarter
  const size_t base = (size_t)bh*(Ln*Dn);
  const size_t wsb  = ((size_t)bh<<15) + ((size_t)c<<13);   // chunk base (halves)

  // K: 32 rows x 64 k; thread -> row sj, 8-wide k group (8 elems/thread)
  {
    const int sj = q*32 + (t>>3);
    const int k0 = (t&7)*8;
    const float* kr = kg + base + (size_t)(c*128 + sj)*Dn + k0;
    const int sx = (sj&7)<<3;
    f32x4 x0 = *(const f32x4*)(kr);
    f32x4 x1 = *(const f32x4*)(kr + 4);
    uint32_t hw[4], lw[4];
    #pragma unroll
    for (int pi=0; pi<4; ++pi){
      float a0 = (pi<2) ? x0[pi*2]   : x1[(pi-2)*2];
      float a1 = (pi<2) ? x0[pi*2+1] : x1[(pi-2)*2+1];
      uint16_t h0 = f2bf(a0), h1 = f2bf(a1);
      hw[pi] = (uint32_t)h0 | ((uint32_t)h1<<16);
      lw[pi] = (uint32_t)f2bf(a0 - bf2f(h0)) | ((uint32_t)f2bf(a1 - bf2f(h1))<<16);
    }
    const size_t di = wsb + (size_t)sj*64 + (k0 ^ sx);   // 8-aligned; XOR flips bits 3-5
    *(u32x4*)(khw + di) = (u32x4){hw[0],hw[1],hw[2],hw[3]};
    *(u32x4*)(klw + di) = (u32x4){lw[0],lw[1],lw[2],lw[3]};
  }

  // V: 4 rows x 2 d per thread -> VT[d][jl], swizzled (same layout as round-12)
  {
    const int j0 = q*32 + (t>>5)*4;    // chunk-local j quad
    const int d0 = (t&31)*2;
    const float* vr = vg + base + (size_t)(c*128 + j0)*Dn + d0;
    f32x2 r0 = *(const f32x2*)(vr);
    f32x2 r1 = *(const f32x2*)(vr + Dn);
    f32x2 r2 = *(const f32x2*)(vr + 2*Dn);
    f32x2 r3 = *(const f32x2*)(vr + 3*Dn);
    #pragma unroll
    for (int qd=0; qd<2; ++qd){
      const int d = d0 + qd;
      u32x2 w; w.x = pack2(r0[qd], r1[qd]); w.y = pack2(r2[qd], r3[qd]);
      *(u32x2*)(vtw + wsb + d*128 + (j0 ^ ((d&7)<<3))) = w;
    }
  }
}

// ---- main: 64 q-rows/block, 4 waves x 16 rows; DMA-staged dbuf chunks (round-12) ----
extern "C" __global__ __launch_bounds__(256, 2)
void attn_main2(const float* __restrict__ qg, const float* __restrict__ mg,
                const uint16_t* __restrict__ khw, const uint16_t* __restrict__ klw,
                const uint16_t* __restrict__ vtw, float* __restrict__ outg)
{
  // 64KB BIG: QK phase KH0[8192] KL0[8192] KH1[8192] KL1[8192] (halves)
  //           PV phase VT0[8192] VT1[8192] P[4 waves][2176]
  // + CMV[512] f32 column-mask terms (lgkm domain; keeps softmax off vmem)
  __shared__ __align__(16) uint16_t BIG[32768];
  __shared__ float CMV[512];

  const int t    = threadIdx.x;
  const int lane = t & 63;
  const int wv   = t >> 6;
  const int li   = lane & 15;
  const int lq   = lane >> 4;
  const int kx   = (li&7)<<3;          // swizzle XOR (halves)

  // XCD swizzle: lin%8 = XCD; XCD k owns bh [k*16,k*16+16)
  const int lin = blockIdx.x + (blockIdx.y << 3);
  const int xcd = lin & 7;
  const int jj  = lin >> 3;
  const int bh  = (xcd << 4) + (jj >> 3);
  const int b   = bh >> 3;
  const int i0  = (jj & 7)*64 + wv*16;

  const size_t base = (size_t)bh*(Ln*Dn);
  const float* mrow = mg + b*Ln;
  const size_t wsbh = (size_t)bh << 15;

  uint16_t* PW = BIG + 16384 + wv*2176;

  auto issueK = [&](int c, int bsel){
    const size_t so = wsbh + ((size_t)c<<13) + (wv<<11) + (lane<<3);
    uint16_t* dh = BIG + bsel*16384 + (wv<<11);
    #pragma unroll
    for (int i=0;i<4;++i){
      gld16(khw + so + i*512, dh + i*512);
      gld16(klw + so + i*512, dh + 8192 + i*512);
    }
  };
  auto issueV = [&](int c, int bsel){
    const size_t so = wsbh + ((size_t)c<<13) + (wv<<11) + (lane<<3);
    uint16_t* dv = BIG + bsel*8192 + (wv<<11);
    #pragma unroll
    for (int i=0;i<4;++i) gld16(vtw + so + i*512, dv + i*512);
  };

  // ---- prologue: Q + mask loads FIRST, then chunk-0 DMA (Q-waits leave DMA alive) ----
  const float* qrow = qg + base + (size_t)(i0 + li)*Dn;
  f32x4 qx0a = *(const f32x4*)(qrow + lq*8);
  f32x4 qx0b = *(const f32x4*)(qrow + lq*8 + 4);
  f32x4 qx1a = *(const f32x4*)(qrow + 32 + lq*8);
  f32x4 qx1b = *(const f32x4*)(qrow + 32 + lq*8 + 4);
  float m0 = mrow[t], m1 = mrow[t+256];
  float mv = mrow[i0 + li];

  issueK(0, 0);

  CMV[t]     = (m0 < -9000.f) ? 1e9f : m0;
  CMV[t+256] = (m1 < -9000.f) ? 1e9f : m1;
  const float rmv = (mv < -9000.f) ? 1e9f : mv;

  short8 qhi[2], qlo[2];
  #pragma unroll
  for (int kt=0; kt<2; ++kt){
    f32x4 xa = kt ? qx1a : qx0a;
    f32x4 xb = kt ? qx1b : qx0b;
    #pragma unroll
    for (int e=0; e<8; ++e){
      float x = (e<4) ? xa[e] : xb[e-4];
      uint16_t h = f2bf(x);
      qhi[kt][e] = (short)h;
      qlo[kt][e] = (short)f2bf(x - bf2f(h));
    }
  }

  f32x4 acc[32];
  #pragma unroll
  for (int j=0; j<32; ++j) acc[j] = (f32x4)0.f;

  // ---- QK: 4 chunks, double-buffered DMA; raw barriers + counted vmcnt ----
  #pragma unroll
  for (int c=0; c<4; ++c){
    if (c<3) issueK(c+1, (c+1)&1);
    if (c<3) asm volatile("s_waitcnt vmcnt(8)" ::: "memory");   // chunk c landed (mine)
    else     asm volatile("s_waitcnt vmcnt(4)" ::: "memory");   // K3 landed; V0 stays in flight
    __builtin_amdgcn_sched_barrier(0);
    __builtin_amdgcn_s_barrier();                                // all waves' portions landed
    __builtin_amdgcn_sched_barrier(0);
    const uint16_t* KHp = BIG + (c&1)*16384;
    const uint16_t* KLp = KHp + 8192;
    __builtin_amdgcn_s_setprio(1);
    #pragma unroll
    for (int jt=0; jt<8; ++jt){
      #pragma unroll
      for (int kt=0; kt<2; ++kt){
        const int idx = (jt*16 + li)*64 + ((kt*32 + lq*8) ^ kx);
        short8 kh = *(const short8*)(KHp + idx);
        short8 kl = *(const short8*)(KLp + idx);
        f32x4 A = acc[c*8+jt];
        A = __builtin_amdgcn_mfma_f32_16x16x32_bf16(kh, qhi[kt], A, 0,0,0);
        A = __builtin_amdgcn_mfma_f32_16x16x32_bf16(kl, qhi[kt], A, 0,0,0);
        A = __builtin_amdgcn_mfma_f32_16x16x32_bf16(kh, qlo[kt], A, 0,0,0);
        acc[c*8+jt] = A;
      }
    }
    __builtin_amdgcn_s_setprio(0);
    __builtin_amdgcn_sched_barrier(0);
    __builtin_amdgcn_s_barrier();                                // readers done before buf reuse
    __builtin_amdgcn_sched_barrier(0);
    if (c==2) issueV(0, 0);   // buf0 free after c=2 close; overlaps chunk-3 compute + softmax
  }

  // ---- mask + scale (CMV from LDS; pure lgkm/VALU — V0 DMA untouched) ----
  #pragma unroll
  for (int jt=0; jt<32; ++jt){
    f32x4 cm = *(const f32x4*)(CMV + jt*16 + lq*4);
    #pragma unroll
    for (int r=0; r<4; ++r)
      acc[jt][r] = (acc[jt][r]*0.125f - rmv) - cm[r];   // fp32 order matches ref
  }

  // ---- softmax over j (wave-local: lane owns full row across quads) ----
  float mx = -3.4e38f;
  #pragma unroll
  for (int jt=0; jt<32; ++jt)
    #pragma unroll
    for (int r=0; r<4; ++r) mx = fmaxf(mx, acc[jt][r]);
  mx = fmaxf(mx, __shfl_xor(mx, 16));
  mx = fmaxf(mx, __shfl_xor(mx, 32));
  float sum = 0.f;
  #pragma unroll
  for (int jt=0; jt<32; ++jt)
    #pragma unroll
    for (int r=0; r<4; ++r){ float e = __expf(acc[jt][r]-mx); acc[jt][r] = e; sum += e; }
  sum += __shfl_xor(sum, 16);
  sum += __shfl_xor(sum, 32);
  const float inv = 1.0f/sum;
  #pragma unroll
  for (int jt=0; jt<32; ++jt) acc[jt] = acc[jt]*inv;   // normalized P (also attn output)

  // ---- PV with per-chunk attn stores; ledger: 8 newest vmem = prev chunk's stores ----
  f32x4 oacc[4];
  #pragma unroll
  for (int dt=0; dt<4; ++dt) oacc[dt] = (f32x4)0.f;

  float* arow = outg + AOFF + (size_t)bh*Ln*Ln + (size_t)(i0+li)*Ln;

  #pragma unroll
  for (int c=0; c<4; ++c){
    // P pack hoisted: pure VALU on acc, done before the wait so the post-barrier
    // path is ds_write -> lgkmcnt -> MFMA with no VALU preamble.
    u32x2 pwreg[8];
    #pragma unroll
    for (int jtl=0; jtl<8; ++jtl){
      const f32x4 p = acc[c*8+jtl];
      pwreg[jtl].x = pack2(p[0], p[1]);
      pwreg[jtl].y = pack2(p[2], p[3]);
    }
    if (c==0) asm volatile("s_waitcnt vmcnt(0)" ::: "memory");   // V0 landed (only V0 out)
    else      asm volatile("s_waitcnt vmcnt(8)" ::: "memory");   // V_c landed; prev stores fly
    __builtin_amdgcn_sched_barrier(0);
    __builtin_amdgcn_s_barrier();                                 // all waves; gates buf reuse
    __builtin_amdgcn_sched_barrier(0);
    if (c<3) issueV(c+1, (c+1)&1);
    #pragma unroll
    for (int jtl=0; jtl<8; ++jtl)                                 // P chunk rows (wave-private)
      *(u32x2*)(PW + li*136 + jtl*16 + lq*4) = pwreg[jtl];
    asm volatile("s_waitcnt lgkmcnt(0)" ::: "memory");            // P visible within wave
    __builtin_amdgcn_sched_barrier(0);
    const uint16_t* VTp = BIG + (c&1)*8192;
    __builtin_amdgcn_s_setprio(1);
    #pragma unroll
    for (int c32=0; c32<4; ++c32){
      short8 pf = *(const short8*)(PW + li*136 + c32*32 + lq*8);           // P^T B-frag
      #pragma unroll
      for (int dt=0; dt<4; ++dt){
        short8 vb = *(const short8*)(VTp + (dt*16+li)*128 + ((c32*32+lq*8) ^ kx)); // V^T A-frag
        oacc[dt] = __builtin_amdgcn_mfma_f32_16x16x32_bf16(vb, pf, oacc[dt], 0,0,0);
      }
    }
    __builtin_amdgcn_s_setprio(0);
    // attn stores for chunk c (8 f32x4/lane) — NORMAL stores: L2 merges the
    // 64B pieces written by this wave this phase into full 128B lines.
    #pragma unroll
    for (int jtl=0; jtl<8; ++jtl)
      *(f32x4*)(arow + (c*8+jtl)*16 + lq*4) = acc[c*8+jtl];
  }

  // ---- store O (O^T C-layout) ----
  #pragma unroll
  for (int dt=0; dt<4; ++dt)
    *(f32x4*)(outg + base + (size_t)(i0+li)*Dn + dt*16 + lq*4) = oacc[dt];
}

// ---------------- fallback (round-5 kernel) if workspace is too small ----------------
#define KSTR  72
#define VTSTR 136
#define FPSTRH 136

extern "C" __global__ __launch_bounds__(256, 2)
void attn_mfma(const float* __restrict__ qg, const float* __restrict__ kg,
               const float* __restrict__ vg, const float* __restrict__ mg,
               float* __restrict__ outg)
{
  __shared__ uint4 ldsraw[(36864 + 2048)/16];
  uint16_t* KHI = (uint16_t*)ldsraw;
  uint16_t* KLO = KHI + 128*KSTR;
  uint16_t* VT  = (uint16_t*)ldsraw;
  float*    CMV = (float*)((char*)ldsraw + 36864);

  const int t    = threadIdx.x;
  const int lane = t & 63;
  const int wv   = t >> 6;
  const int li   = lane & 15;
  const int lq   = lane >> 4;

  const int lin = blockIdx.x + (blockIdx.y << 3);
  const int xcd = lin & 7;
  const int jj  = lin >> 3;
  const int bh  = (xcd << 4) + (jj >> 3);
  const int b   = bh >> 3;
  const int i0  = (jj & 7)*64 + wv*16;

  const size_t base = (size_t)bh*(Ln*Dn);
  const float* mrow = mg + b*Ln;

  uint16_t* PW = (uint16_t*)((char*)ldsraw + 17408 + wv*(16*FPSTRH*2));

  {
    float m0 = mrow[t], m1 = mrow[t+256];
    CMV[t]     = (m0 < -9000.f) ? 1e9f : m0;
    CMV[t+256] = (m1 < -9000.f) ? 1e9f : m1;
  }

  short8 qhi[2], qlo[2];
  {
    const float* qrow = qg + base + (size_t)(i0 + li)*Dn;
    #pragma unroll
    for (int kt=0; kt<2; ++kt){
      const float* p = qrow + kt*32 + lq*8;
      f32x4 x0 = *(const f32x4*)p;
      f32x4 x1 = *(const f32x4*)(p+4);
      #pragma unroll
      for (int e=0; e<8; ++e){
        float x = (e<4) ? x0[e] : x1[e-4];
        uint16_t h = f2bf(x);
        qhi[kt][e] = (short)h;
        qlo[kt][e] = (short)f2bf(x - bf2f(h));
      }
    }
  }

  f32x4 acc[32];
  #pragma unroll
  for (int j=0; j<32; ++j) acc[j] = (f32x4)0.f;

  const int sj = t>>1, skh = t&1;
  #pragma unroll
  for (int c=0; c<4; ++c){
    __syncthreads();
    {
      const float* kr = kg + base + (size_t)(c*128 + sj)*Dn + skh*32;
      uint16_t* dhi = KHI + sj*KSTR + skh*32;
      uint16_t* dlo = KLO + sj*KSTR + skh*32;
      #pragma unroll
      for (int w2=0; w2<4; ++w2){
        f32x4 x0 = *(const f32x4*)(kr + w2*8);
        f32x4 x1 = *(const f32x4*)(kr + w2*8 + 4);
        uint32_t hw[4], lw[4];
        #pragma unroll
        for (int pi=0; pi<4; ++pi){
          float a0 = (pi<2) ? x0[pi*2]   : x1[(pi-2)*2];
          float a1 = (pi<2) ? x0[pi*2+1] : x1[(pi-2)*2+1];
          uint16_t h0 = f2bf(a0), h1 = f2bf(a1);
          hw[pi] = (uint32_t)h0 | ((uint32_t)h1<<16);
          lw[pi] = (uint32_t)f2bf(a0 - bf2f(h0)) | ((uint32_t)f2bf(a1 - bf2f(h1))<<16);
        }
        *(u32x4*)(dhi + w2*8) = (u32x4){hw[0],hw[1],hw[2],hw[3]};
        *(u32x4*)(dlo + w2*8) = (u32x4){lw[0],lw[1],lw[2],lw[3]};
      }
    }
    __syncthreads();
    #pragma unroll
    for (int jt=0; jt<8; ++jt){
      #pragma unroll
      for (int kt=0; kt<2; ++kt){
        const int off = (jt*16 + li)*KSTR + kt*32 + lq*8;
        short8 kh = *(const short8*)(KHI + off);
        short8 kl = *(const short8*)(KLO + off);
        f32x4 A = acc[c*8+jt];
        A = __builtin_amdgcn_mfma_f32_16x16x32_bf16(kh, qhi[kt], A, 0,0,0);
        A = __builtin_amdgcn_mfma_f32_16x16x32_bf16(kl, qhi[kt], A, 0,0,0);
        A = __builtin_amdgcn_mfma_f32_16x16x32_bf16(kh, qlo[kt], A, 0,0,0);
        acc[c*8+jt] = A;
      }
    }
  }

  {
    float mv = mrow[i0 + li];
    const float rmv = (mv < -9000.f) ? 1e9f : mv;
    #pragma unroll
    for (int jt=0; jt<32; ++jt){
      f32x4 cm = *(const f32x4*)(CMV + jt*16 + lq*4);
      #pragma unroll
      for (int r=0; r<4; ++r)
        acc[jt][r] = (acc[jt][r]*0.125f - rmv) - cm[r];
    }
  }
  float mx = -3.4e38f;
  #pragma unroll
  for (int jt=0; jt<32; ++jt)
    #pragma unroll
    for (int r=0; r<4; ++r) mx = fmaxf(mx, acc[jt][r]);
  mx = fmaxf(mx, __shfl_xor(mx, 16));
  mx = fmaxf(mx, __shfl_xor(mx, 32));
  float sum = 0.f;
  #pragma unroll
  for (int jt=0; jt<32; ++jt)
    #pragma unroll
    for (int r=0; r<4; ++r){ float e = __expf(acc[jt][r]-mx); acc[jt][r] = e; sum += e; }
  sum += __shfl_xor(sum, 16);
  sum += __shfl_xor(sum, 32);
  const float inv = 1.0f/sum;

  {
    float* arow = outg + AOFF + (size_t)bh*Ln*Ln + (size_t)(i0+li)*Ln;
    #pragma unroll
    for (int jt=0; jt<32; ++jt){
      f32x4 p = acc[jt]*inv;
      acc[jt] = p;
      *(f32x4*)(arow + jt*16 + lq*4) = p;
    }
  }

  f32x4 oacc[4];
  #pragma unroll
  for (int dt=0; dt<4; ++dt) oacc[dt] = (f32x4)0.f;

  #pragma unroll
  for (int c=0; c<4; ++c){
    __syncthreads();
    #pragma unroll
    for (int it=0; it<2; ++it){
      const int j0 = (t>>4)*4 + it*64;
      const int d0 = (t&15)*4;
      const float* vr = vg + base + (size_t)(c*128 + j0)*Dn + d0;
      f32x4 r0 = *(const f32x4*)(vr);
      f32x4 r1 = *(const f32x4*)(vr + Dn);
      f32x4 r2 = *(const f32x4*)(vr + 2*Dn);
      f32x4 r3 = *(const f32x4*)(vr + 3*Dn);
      #pragma unroll
      for (int qd=0; qd<4; ++qd){
        u32x2 w; w.x = pack2(r0[qd], r1[qd]); w.y = pack2(r2[qd], r3[qd]);
        *(u32x2*)(VT + (d0+qd)*VTSTR + j0) = w;
      }
    }
    __syncthreads();
    #pragma unroll
    for (int jtl=0; jtl<8; ++jtl){
      const f32x4 p = acc[c*8+jtl];
      u32x2 w; w.x = pack2(p[0], p[1]); w.y = pack2(p[2], p[3]);
      *(u32x2*)(PW + li*FPSTRH + jtl*16 + lq*4) = w;
    }
    asm volatile("s_waitcnt lgkmcnt(0)" ::: "memory");
    #pragma unroll
    for (int c32=0; c32<4; ++c32){
      short8 pf = *(const short8*)(PW + li*FPSTRH + c32*32 + lq*8);
      #pragma unroll
      for (int dt=0; dt<4; ++dt){
        short8 vb = *(const short8*)(VT + (dt*16+li)*VTSTR + c32*32 + lq*8);
        oacc[dt] = __builtin_amdgcn_mfma_f32_16x16x32_bf16(vb, pf, oacc[dt], 0,0,0);
      }
    }
  }

  #pragma unroll
  for (int dt=0; dt<4; ++dt)
    *(f32x4*)(outg + base + (size_t)(i0+li)*Dn + dt*16 + lq*4) = oacc[dt];
}

extern "C" void kernel_launch(void* const* d_in, const int* in_sizes, int n_in,
                              void* d_out, int out_size, void* d_ws, size_t ws_size,
                              hipStream_t stream)
{
  (void)in_sizes; (void)n_in; (void)out_size;
  const float* qg = (const float*)d_in[0];
  const float* kg = (const float*)d_in[1];
  const float* vg = (const float*)d_in[2];
  const float* mg = (const float*)d_in[3];
  float* outg = (float*)d_out;

  const size_t WS_NEED = 25165824;   // KHI 8.39MB + KLO 8.39MB + VT 8.39MB
  if (d_ws && ws_size >= WS_NEED){
    uint16_t* khw = (uint16_t*)d_ws;
    uint16_t* klw = (uint16_t*)((char*)d_ws + 8388608);
    uint16_t* vtw = (uint16_t*)((char*)d_ws + 16777216);
    attn_prep<<<dim3(16, BHn), 256, 0, stream>>>(kg, vg, khw, klw, vtw);
    attn_main2<<<dim3(Ln/64, BHn), 256, 0, stream>>>(qg, mg, khw, klw, vtw, outg);
  } else {
    attn_mfma<<<dim3(Ln/64, BHn), 256, 0, stream>>>(qg, kg, vg, mg, outg);
  }
}